// Round 1
// baseline (120.314 us; speedup 1.0000x reference)
//
#include <hip/hip_runtime.h>

// Problem constants (reference: B=32, L=64, C=4)
#define BB 32
#define LL 64
#define CC 4
#define LC (LL * CC)          // 256
#define NPAIR (LL * (LL - 1) / 2)  // 2016 pairs u<v

// Kernel A: recover one-hot indices p[b][l] = l*C + argmax_c x[b,l,c],
// and zero the output (d_out is poisoned 0xAA before every launch).
__global__ __launch_bounds__(256) void setup_kernel(
    const float* __restrict__ x, float* __restrict__ out, int* __restrict__ p)
{
    int gid = blockIdx.x * 256 + threadIdx.x;
    if (gid < BB * LL) {
        int b = gid >> 6;
        int l = gid & 63;
        const float* xr = x + b * LC + l * CC;
        int c = 0;
        float best = xr[0];
#pragma unroll
        for (int k = 1; k < CC; ++k) {
            float v = xr[k];
            if (v > best) { best = v; c = k; }
        }
        p[gid] = l * CC + c;
    }
    if (gid < BB) out[gid] = 0.0f;
}

// Kernel B: one block per (b, pair-chunk). Each thread owns one (u,v) pair
// (u<v), gathers theta2[p[u]*256+p[v]] and loops w=v+1..63 gathering
// theta3[p[u]*65536 + p[v]*256 + p[w]] (w innermost => ~16B address stride,
// good cacheline reuse). Block-reduce, one atomicAdd per block.
__global__ __launch_bounds__(256) void main_kernel(
    const float* __restrict__ t0, const float* __restrict__ t1,
    const float* __restrict__ t2, const float* __restrict__ t3,
    const int* __restrict__ p, float* __restrict__ out)
{
    const int b = blockIdx.x;
    const int tid = threadIdx.x;

    __shared__ int sp[LL];
    if (tid < LL) sp[tid] = p[b * LL + tid];
    __syncthreads();

    float acc = 0.0f;
    int t = blockIdx.y * 256 + tid;
    if (t < NPAIR) {
        // decode triangular index t = v*(v-1)/2 + u, 0 <= u < v < L
        int v = (int)((1.0f + sqrtf(8.0f * (float)t + 1.0f)) * 0.5f);
        while (v * (v - 1) / 2 > t) --v;
        while ((v + 1) * v / 2 <= t) ++v;
        int u = t - v * (v - 1) / 2;

        int pu = sp[u];
        int pv = sp[v];
        acc = t2[pu * LC + pv];

        const float* __restrict__ t3row = t3 + (size_t)pu * (LC * LC) + pv * LC;
        for (int w = v + 1; w < LL; ++w) {
            acc += t3row[sp[w]];
        }
    }
    // order-1 + constant term handled once per b (chunk 0)
    if (blockIdx.y == 0) {
        if (tid < LL) acc += t1[sp[tid]];
        if (tid == 0) acc += t0[0];
    }

    // wave (64-lane) shuffle reduction, then cross-wave via LDS
    for (int off = 32; off > 0; off >>= 1) acc += __shfl_down(acc, off, 64);
    __shared__ float wsum[4];
    if ((tid & 63) == 0) wsum[tid >> 6] = acc;
    __syncthreads();
    if (tid == 0) atomicAdd(&out[b], wsum[0] + wsum[1] + wsum[2] + wsum[3]);
}

extern "C" void kernel_launch(void* const* d_in, const int* in_sizes, int n_in,
                              void* d_out, int out_size, void* d_ws, size_t ws_size,
                              hipStream_t stream) {
    const float* x  = (const float*)d_in[0];  // (B, L*C)
    const float* t0 = (const float*)d_in[1];  // (1,)
    const float* t1 = (const float*)d_in[2];  // (L, C)
    const float* t2 = (const float*)d_in[3];  // (L, C, L, C)
    const float* t3 = (const float*)d_in[4];  // (L, C, L, C, L, C)
    float* out = (float*)d_out;               // (B, 1)
    int* p = (int*)d_ws;                      // B*L ints = 8 KB

    setup_kernel<<<(BB * LL + 255) / 256, 256, 0, stream>>>(x, out, p);
    main_kernel<<<dim3(BB, 8), 256, 0, stream>>>(t0, t1, t2, t3, p, out);
}

// Round 2
// 110.647 us; speedup vs baseline: 1.0874x; 1.0874x over previous
//
#include <hip/hip_runtime.h>

// Problem constants (reference: B=32, L=64, C=4)
#define BB 32
#define LL 64
#define CC 4
#define LC 256                 // L*C
#define NPAIR 2016             // L*(L-1)/2 pairs u<v
#define NTASK 4032             // 2 half-tasks per pair
#define CHUNK 126              // tasks per chunk; 32 chunks total
#define NCHUNK 32
#define YBLK 16                // blocks per b; block y handles chunks y and 31-y

// One block per (b, y). Each thread owns half of one (u,v) pair's w-loop.
// Key identity: sp[w] = 4w + c, so theta3 row accesses are one element per
// 16B slot of a CONTIGUOUS row tail -> dense float4 reads + component select
// (no gather, no LDS load in the address path).
__global__ __launch_bounds__(256) void main_kernel(
    const float* __restrict__ x,
    const float* __restrict__ t0, const float* __restrict__ t1,
    const float* __restrict__ t2, const float* __restrict__ t3,
    float* __restrict__ ws)
{
    const int b = blockIdx.x;
    const int y = blockIdx.y;
    const int tid = threadIdx.x;

    __shared__ int sp[LL];
    if (tid < LL) {
        const float* xr = x + b * LC + tid * CC;
        int c = 0; float best = xr[0];
#pragma unroll
        for (int k = 1; k < CC; ++k) { float v = xr[k]; if (v > best) { best = v; c = k; } }
        sp[tid] = tid * CC + c;
    }
    __syncthreads();

    float acc = 0.0f;
    const int lane = tid & 127;
    const int chunk = (tid < 128) ? y : (NCHUNK - 1 - y);  // pair long+short chunks
    if (lane < CHUNK) {
        int s = chunk * CHUNK + lane;
        int t = s >> 1;
        int h = s & 1;
        // decode triangular index t = v*(v-1)/2 + u, 0 <= u < v < L
        int v = (int)((1.0f + sqrtf(8.0f * (float)t + 1.0f)) * 0.5f);
        while (v * (v - 1) / 2 > t) --v;
        while ((v + 1) * v / 2 <= t) ++v;
        int u = t - v * (v - 1) / 2;

        int pu = sp[u], pv = sp[v];
        int n = 63 - v;                  // w-loop length, w in [v+1, 64)
        int half1 = (n + 1) >> 1;
        int wlo = v + 1 + (h ? half1 : 0);
        int whi = h ? 64 : (v + 1 + half1);
        if (h == 0) acc += t2[pu * LC + pv];

        const float4* __restrict__ row =
            (const float4*)(t3 + (size_t)pu * (LC * LC) + (size_t)pv * LC);
#pragma unroll 4
        for (int w = wlo; w < whi; ++w) {
            float4 f = row[w];           // dense, 16B-aligned, sequential
            int c = sp[w] & 3;
            acc += (c == 0) ? f.x : (c == 1) ? f.y : (c == 2) ? f.z : f.w;
        }
    }
    // order-1 + constant term: block y==0's second half (its chunk-31 tasks are tiny)
    if (y == 0 && tid >= 128 && tid < 192) {
        acc += t1[sp[tid - 128]];
        if (tid == 128) acc += t0[0];
    }

    // block reduction: wave shuffle then LDS
    for (int off = 32; off > 0; off >>= 1) acc += __shfl_down(acc, off, 64);
    __shared__ float wsum[4];
    if ((tid & 63) == 0) wsum[tid >> 6] = acc;
    __syncthreads();
    if (tid == 0) ws[b * YBLK + y] = wsum[0] + wsum[1] + wsum[2] + wsum[3];
}

// Sum the 16 per-block partials for each b. No atomics, no zero-init needed.
__global__ __launch_bounds__(512) void reduce_kernel(
    const float* __restrict__ ws, float* __restrict__ out)
{
    int tid = threadIdx.x;               // 512 = 32 b * 16 slots
    int b = tid >> 4, slot = tid & 15;
    float v = ws[b * YBLK + slot];
#pragma unroll
    for (int off = 8; off > 0; off >>= 1) v += __shfl_down(v, off, 16);
    if (slot == 0) out[b] = v;
}

extern "C" void kernel_launch(void* const* d_in, const int* in_sizes, int n_in,
                              void* d_out, int out_size, void* d_ws, size_t ws_size,
                              hipStream_t stream) {
    const float* x  = (const float*)d_in[0];  // (B, L*C)
    const float* t0 = (const float*)d_in[1];  // (1,)
    const float* t1 = (const float*)d_in[2];  // (L, C)
    const float* t2 = (const float*)d_in[3];  // (L, C, L, C)
    const float* t3 = (const float*)d_in[4];  // (L, C, L, C, L, C)
    float* out = (float*)d_out;               // (B, 1)
    float* ws = (float*)d_ws;                 // 32*16 partials

    main_kernel<<<dim3(BB, YBLK), 256, 0, stream>>>(x, t0, t1, t2, t3, ws);
    reduce_kernel<<<1, 512, 0, stream>>>(ws, out);
}